// Round 5
// baseline (142.057 us; speedup 1.0000x reference)
//
#include <hip/hip_runtime.h>
#include <hip/hip_bf16.h>

#define D 128
#define MARGIN 0.5f
#define NSPLIT 16      // j-splits; block j-window = 8192/16 = 512 cols
#define JSPAN 512      // n / NSPLIT (n = 8192 fixed by harness)

typedef __attribute__((ext_vector_type(8))) short bf16x8;
typedef __attribute__((ext_vector_type(4))) float f32x4;

// ---------------- prep: bf16 convert + sq + out init ----------------
__global__ void prep_kernel(const float* __restrict__ x,
                            float* __restrict__ sq,
                            __hip_bfloat16* __restrict__ xb,
                            float* __restrict__ out, int n) {
    int tid = threadIdx.x;
    int row = blockIdx.x * 4 + (tid >> 6);
    int lane = tid & 63;
    const float2* xr = (const float2*)(x + (size_t)row * D);
    float2 v = xr[lane];
    __hip_bfloat162 b2;
    b2.x = __float2bfloat16(v.x);
    b2.y = __float2bfloat16(v.y);
    ((__hip_bfloat162*)(xb + (size_t)row * D))[lane] = b2;
    float s = v.x * v.x + v.y * v.y;
    #pragma unroll
    for (int o = 32; o > 0; o >>= 1) s += __shfl_xor(s, o, 64);
    if (lane == 0) sq[row] = s;
    if (blockIdx.x == 0 && tid == 0) *out = 0.0f;
}

// ---------------- gram: R2 pipeline + wave-rotation de-convoy (R9) --------
// R8's counters pinned the diagnosis: barrier-locked lockstep waves execute
// each phase as three SERIAL per-CU bursts (LDS flood ~1536cyc -> MFMA flood
// ~1241 -> VALU epilogue ~800), so pipes never overlap (sum ~3600cyc/phase
// ~= measured 32us gram vs 10-12us overlapped floor). Fix: wave `wid` walks
// the phase sub-tiles in ROTATED order (jt ^= wid&1, ks rotated by wid) so
// waves occupy different pipes at any instant. Rotation is data-safe (same
// read-only buffer) and numerically safe (permutes a commutative fp32
// accumulation chain).
// Base structure unchanged from the verified R2 kernel: mt=2 (32 i-rows per
// wave), 16 half-tile phases of 32 j-rows (8KB), 4-slot LDS ring, counted
// s_waitcnt vmcnt(4) (tiles h+1,h+2 in flight, never drain to 0 in steady
// state), 1 barrier/phase, setprio around MFMA cluster, global_load_lds
// width=16 with XOR swizzle on the per-lane GLOBAL src addr (LDS dest must
// be wave-uniform base + lane*16).
// Tail: plain per-(row,jsplit) partial stores (R8's win kept) -- no 262K
// device-atomic convoy; final_kernel reduces the NSPLIT slabs.
__launch_bounds__(256, 4)
__global__ void gram_kernel(const __hip_bfloat16* __restrict__ xb,
                            const float* __restrict__ sq,
                            const int* __restrict__ tgt,
                            float* __restrict__ pap,
                            float* __restrict__ pan, int n) {
    __shared__ __align__(16) __hip_bfloat16 Bs[4][32 * D];  // 4 x 8KB ring
    __shared__ float sqs[JSPAN];
    __shared__ int   tgs[JSPAN];

    const int tid  = threadIdx.x;
    const int wid  = tid >> 6;
    const int lane = tid & 63;
    const int quad = lane >> 4;
    const int l    = lane & 15;
    const int i0   = blockIdx.x * 128;
    const int j0   = blockIdx.y * JSPAN;
    const int rowbase = i0 + wid * 32;

    // A fragments, register-resident: lane holds A[m=l][k=quad*8+r]
    bf16x8 afrag[2][4];
    {
        const __hip_bfloat16* abase = xb + (size_t)(rowbase + l) * D + quad * 8;
        #pragma unroll
        for (int mt = 0; mt < 2; ++mt)
            #pragma unroll
            for (int ks = 0; ks < 4; ++ks)
                afrag[mt][ks] = *(const bf16x8*)(abase + (size_t)mt * 16 * D + ks * 32);
    }

    int li[2][4];
    #pragma unroll
    for (int mt = 0; mt < 2; ++mt)
        #pragma unroll
        for (int reg = 0; reg < 4; ++reg)
            li[mt][reg] = tgt[rowbase + mt * 16 + quad * 4 + reg];

    float lap[8], lan[8];
    #pragma unroll
    for (int k = 0; k < 8; ++k) { lap[k] = -1e30f; lan[k] = 1e30f; }

    // staging: per half-tile (32 rows = 512 chunks of 16B), wave wid owns
    // chunks q = wid*128 + i*64 + lane (2 glds/wave). LDS chunk q holds
    // global (row r=q>>4, chunk c=(q&15)^(r&15)) of the half-tile.
    const char* xbb = (const char*)xb;

    #define PREF_HALF(h)                                                      \
        do {                                                                  \
            const int s_ = (h) & 3;                                           \
            _Pragma("unroll")                                                 \
            for (int i_ = 0; i_ < 2; ++i_) {                                  \
                int q_ = wid * 128 + i_ * 64 + lane;                          \
                int r_ = q_ >> 4;                                             \
                int c_ = (q_ & 15) ^ (r_ & 15);                               \
                const char* g_ = xbb + (size_t)(j0 + (h) * 32 + r_) * 256     \
                                     + (size_t)c_ * 16;                       \
                char* l_ = (char*)Bs + (size_t)s_ * 8192                      \
                         + (size_t)(wid * 128 + i_ * 64) * 16;                \
                __builtin_amdgcn_global_load_lds(                             \
                    (const __attribute__((address_space(1))) void*)g_,        \
                    (__attribute__((address_space(3))) void*)l_, 16, 0, 0);   \
            }                                                                 \
        } while (0)

    // frag read: global row rr=jt*16+l of half, k-chunk kc=ks*4+quad lives
    // at LDS chunk rr*16 + (kc ^ (rr&15)); rr&15 == l.
    // ROTATION: jtr = jt ^ (wid&1); ksr = (ks+wid)&3 -- per-wave sub-tile
    // order differs so the CU's waves hit LDS/MFMA/VALU pipes staggered.
    #define COMP_HALF(h)                                                      \
        do {                                                                  \
            const char* Bb_ = (const char*)Bs + (size_t)((h) & 3) * 8192;     \
            _Pragma("unroll")                                                 \
            for (int jt = 0; jt < 2; ++jt) {                                  \
                const int jtr = jt ^ (wid & 1);                               \
                f32x4 acc0 = (f32x4){0.f, 0.f, 0.f, 0.f};                     \
                f32x4 acc1 = (f32x4){0.f, 0.f, 0.f, 0.f};                     \
                __builtin_amdgcn_s_setprio(1);                                \
                _Pragma("unroll")                                             \
                for (int ks = 0; ks < 4; ++ks) {                              \
                    const int ksr = (ks + wid) & 3;                           \
                    int q = (jtr * 16 + l) * 16 + ((ksr * 4 + quad) ^ l);     \
                    bf16x8 bfr = *(const bf16x8*)(Bb_ + (size_t)q * 16);      \
                    acc0 = __builtin_amdgcn_mfma_f32_16x16x32_bf16(           \
                        afrag[0][ksr], bfr, acc0, 0, 0, 0);                   \
                    acc1 = __builtin_amdgcn_mfma_f32_16x16x32_bf16(           \
                        afrag[1][ksr], bfr, acc1, 0, 0, 0);                   \
                }                                                             \
                __builtin_amdgcn_s_setprio(0);                                \
                int jb_ = (h) * 32 + jtr * 16;                                \
                float sjc = sqs[jb_ + l];                                     \
                int   tjc = tgs[jb_ + l];                                     \
                _Pragma("unroll")                                             \
                for (int reg = 0; reg < 4; ++reg) {                           \
                    float t0 = fmaf(-2.0f, acc0[reg], sjc);                   \
                    float t1 = fmaf(-2.0f, acc1[reg], sjc);                   \
                    bool s0 = (li[0][reg] == tjc);                            \
                    bool s1 = (li[1][reg] == tjc);                            \
                    lap[reg]     = fmaxf(lap[reg],     s0 ? t0 : -1e30f);     \
                    lan[reg]     = fminf(lan[reg],     s0 ? 1e30f : t0);      \
                    lap[4 + reg] = fmaxf(lap[4 + reg], s1 ? t1 : -1e30f);     \
                    lan[4 + reg] = fminf(lan[4 + reg], s1 ? 1e30f : t1);      \
                }                                                             \
            }                                                                 \
        } while (0)

    // prologue: 3 half-tiles in flight + metadata staged
    PREF_HALF(0);
    PREF_HALF(1);
    PREF_HALF(2);
    sqs[tid]       = sq[j0 + tid];
    sqs[tid + 256] = sq[j0 + tid + 256];
    tgs[tid]       = tgt[j0 + tid];
    tgs[tid + 256] = tgt[j0 + tid + 256];
    asm volatile("s_waitcnt lgkmcnt(0)" ::: "memory");

    // steady-state phases: counted vmcnt, one barrier per phase
    for (int h = 0; h < 14; ++h) {
        asm volatile("s_waitcnt vmcnt(4)" ::: "memory");
        __builtin_amdgcn_s_barrier();
        asm volatile("" ::: "memory");       // no load hoisting above barrier
        if (h < 13) PREF_HALF(h + 3);
        COMP_HALF(h);
    }
    // tail phases: drain 2 -> 0
    asm volatile("s_waitcnt vmcnt(2)" ::: "memory");
    __builtin_amdgcn_s_barrier();
    asm volatile("" ::: "memory");
    COMP_HALF(14);
    asm volatile("s_waitcnt vmcnt(0)" ::: "memory");
    __builtin_amdgcn_s_barrier();
    asm volatile("" ::: "memory");
    COMP_HALF(15);

    #undef PREF_HALF
    #undef COMP_HALF

    // reduce across 16 column-lanes (xor<16 stays within quad group),
    // then plain partial store (no atomics)
    #pragma unroll
    for (int mt = 0; mt < 2; ++mt)
        #pragma unroll
        for (int reg = 0; reg < 4; ++reg) {
            float p = lap[mt * 4 + reg], q = lan[mt * 4 + reg];
            #pragma unroll
            for (int o = 1; o < 16; o <<= 1) {
                p = fmaxf(p, __shfl_xor(p, o, 64));
                q = fminf(q, __shfl_xor(q, o, 64));
            }
            if (l == mt * 4 + reg) {   // one writer lane per quad
                int gi = rowbase + mt * 16 + quad * 4 + reg;
                float s = sq[gi];
                pap[(size_t)blockIdx.y * n + gi] = fmaxf(s + p, 0.0f);
                pan[(size_t)blockIdx.y * n + gi] = fmaxf(s + q, 0.0f);
            }
        }
}

// ---------------- final: reduce partials, sum relu(ap - an + margin) -----
__global__ void final_kernel(const float* __restrict__ pap,
                             const float* __restrict__ pan,
                             float* __restrict__ out, int n) {
    int i = blockIdx.x * blockDim.x + threadIdx.x;
    float p = pap[i], q = pan[i];
    #pragma unroll
    for (int s = 1; s < NSPLIT; ++s) {
        p = fmaxf(p, pap[(size_t)s * n + i]);
        q = fminf(q, pan[(size_t)s * n + i]);
    }
    float v = fmaxf(p - q + MARGIN, 0.0f);
    #pragma unroll
    for (int o = 32; o > 0; o >>= 1) v += __shfl_xor(v, o, 64);
    __shared__ float ws[4];
    int lane = threadIdx.x & 63, w = threadIdx.x >> 6;
    if (lane == 0) ws[w] = v;
    __syncthreads();
    if (threadIdx.x == 0) atomicAdd(out, ws[0] + ws[1] + ws[2] + ws[3]);
}

extern "C" void kernel_launch(void* const* d_in, const int* in_sizes, int n_in,
                              void* d_out, int out_size, void* d_ws, size_t ws_size,
                              hipStream_t stream) {
    const float* x   = (const float*)d_in[0];
    const int*   tgt = (const int*)d_in[1];
    float* out = (float*)d_out;
    const int n = in_sizes[1];              // 8192

    // ws layout: sq [n*4] | pap [n*NSPLIT*4] | pan [n*NSPLIT*4] | xb [n*D*2]
    float*          sq  = (float*)d_ws;
    float*          pap = (float*)((char*)d_ws + (size_t)n * 4);
    float*          pan = (float*)((char*)d_ws + (size_t)n * 4 + (size_t)n * NSPLIT * 4);
    __hip_bfloat16* xb  = (__hip_bfloat16*)((char*)d_ws + (size_t)n * 4 + (size_t)n * NSPLIT * 8);

    prep_kernel<<<n / 4, 256, 0, stream>>>(x, sq, xb, out, n);
    dim3 grid(n / 128, NSPLIT);
    gram_kernel<<<grid, 256, 0, stream>>>(xb, sq, tgt, pap, pan, n);
    final_kernel<<<n / 256, 256, 0, stream>>>(pap, pan, out, n);
}

// Round 6
// 87.491 us; speedup vs baseline: 1.6237x; 1.6237x over previous
//
#include <hip/hip_runtime.h>
#include <hip/hip_bf16.h>

#define D 128
#define MARGIN 0.5f
#define NSPLIT 16      // j-splits; block j-window = 8192/16 = 512 cols
#define JSPAN 512      // n / NSPLIT (n = 8192 fixed by harness)

typedef __attribute__((ext_vector_type(8))) short bf16x8;
typedef __attribute__((ext_vector_type(4))) float f32x4;

// ---------------- prep: bf16 convert + sq + out init ----------------
__global__ void prep_kernel(const float* __restrict__ x,
                            float* __restrict__ sq,
                            __hip_bfloat16* __restrict__ xb,
                            float* __restrict__ out, int n) {
    int tid = threadIdx.x;
    int row = blockIdx.x * 4 + (tid >> 6);
    int lane = tid & 63;
    const float2* xr = (const float2*)(x + (size_t)row * D);
    float2 v = xr[lane];
    __hip_bfloat162 b2;
    b2.x = __float2bfloat16(v.x);
    b2.y = __float2bfloat16(v.y);
    ((__hip_bfloat162*)(xb + (size_t)row * D))[lane] = b2;
    float s = v.x * v.x + v.y * v.y;
    #pragma unroll
    for (int o = 32; o > 0; o >>= 1) s += __shfl_xor(s, o, 64);
    if (lane == 0) sq[row] = s;
    if (blockIdx.x == 0 && tid == 0) *out = 0.0f;
}

// ---------------- gram: verified R2 structure + block phase-stagger -------
// R5 post-mortem: runtime-indexed afrag (rule #20) poisoned the rotation
// probe (VGPR 64, VALUBusy 75%, gram 90us). This version restores the
// VERIFIED R2 compute structure exactly (static indices everywhere; gram
// ~33us, total 86.7) and adds ONE additive, correctness-neutral lever:
// co-resident blocks (dispatch rounds 0..3 of the 1024-block grid under
// round-robin XCD dispatch) sleep 0/960/1920/2880 cyc after issuing their
// prologue prefetches. Theory (R4-counter-backed): per phase the three pipe
// costs are nearly equal (LDS 1536 cyc/CU, MFMA 1242 cyc/SIMD, VALU 1360
// cyc/SIMD) but lockstep waves execute them as SERIAL per-CU bursts
// (~4800 cyc/phase measured = serial sum). Staggering blocks by ~1 burst
// anti-aligns the quartet so bursts overlap across blocks.
// Structure: mt=2 (32 i-rows/wave), 16 half-tile phases of 32 j-rows (8KB),
// 4-slot LDS ring, counted s_waitcnt vmcnt(4) (tiles h+1,h+2 in flight,
// never drained to 0 in steady state), 1 barrier/phase, setprio around the
// MFMA cluster, global_load_lds width=16 with XOR swizzle on the per-lane
// GLOBAL src addr (LDS dest must be wave-uniform base + lane*16).
// Tail: plain per-(row,jsplit) partial stores (no 262K-atomic convoy);
// final_kernel reduces the NSPLIT slabs.
__launch_bounds__(256, 4)
__global__ void gram_kernel(const __hip_bfloat16* __restrict__ xb,
                            const float* __restrict__ sq,
                            const int* __restrict__ tgt,
                            float* __restrict__ pap,
                            float* __restrict__ pan, int n) {
    __shared__ __align__(16) __hip_bfloat16 Bs[4][32 * D];  // 4 x 8KB ring
    __shared__ float sqs[JSPAN];
    __shared__ int   tgs[JSPAN];

    const int tid  = threadIdx.x;
    const int wid  = tid >> 6;
    const int lane = tid & 63;
    const int quad = lane >> 4;
    const int l    = lane & 15;
    const int i0   = blockIdx.x * 128;
    const int j0   = blockIdx.y * JSPAN;
    const int rowbase = i0 + wid * 32;

    // A fragments, register-resident: lane holds A[m=l][k=quad*8+r]
    bf16x8 afrag[2][4];
    {
        const __hip_bfloat16* abase = xb + (size_t)(rowbase + l) * D + quad * 8;
        #pragma unroll
        for (int mt = 0; mt < 2; ++mt)
            #pragma unroll
            for (int ks = 0; ks < 4; ++ks)
                afrag[mt][ks] = *(const bf16x8*)(abase + (size_t)mt * 16 * D + ks * 32);
    }

    int li[2][4];
    #pragma unroll
    for (int mt = 0; mt < 2; ++mt)
        #pragma unroll
        for (int reg = 0; reg < 4; ++reg)
            li[mt][reg] = tgt[rowbase + mt * 16 + quad * 4 + reg];

    float lap[8], lan[8];
    #pragma unroll
    for (int k = 0; k < 8; ++k) { lap[k] = -1e30f; lan[k] = 1e30f; }

    // staging: per half-tile (32 rows = 512 chunks of 16B), wave wid owns
    // chunks q = wid*128 + i*64 + lane (2 glds/wave). LDS chunk q holds
    // global (row r=q>>4, chunk c=(q&15)^(r&15)) of the half-tile.
    const char* xbb = (const char*)xb;

    #define PREF_HALF(h)                                                      \
        do {                                                                  \
            const int s_ = (h) & 3;                                           \
            _Pragma("unroll")                                                 \
            for (int i_ = 0; i_ < 2; ++i_) {                                  \
                int q_ = wid * 128 + i_ * 64 + lane;                          \
                int r_ = q_ >> 4;                                             \
                int c_ = (q_ & 15) ^ (r_ & 15);                               \
                const char* g_ = xbb + (size_t)(j0 + (h) * 32 + r_) * 256     \
                                     + (size_t)c_ * 16;                       \
                char* l_ = (char*)Bs + (size_t)s_ * 8192                      \
                         + (size_t)(wid * 128 + i_ * 64) * 16;                \
                __builtin_amdgcn_global_load_lds(                             \
                    (const __attribute__((address_space(1))) void*)g_,        \
                    (__attribute__((address_space(3))) void*)l_, 16, 0, 0);   \
            }                                                                 \
        } while (0)

    // frag read: global row rr=jt*16+l of half, k-chunk kc=ks*4+quad lives
    // at LDS chunk rr*16 + (kc ^ (rr&15)); rr&15 == l. ALL STATIC INDICES.
    #define COMP_HALF(h)                                                      \
        do {                                                                  \
            const char* Bb_ = (const char*)Bs + (size_t)((h) & 3) * 8192;     \
            _Pragma("unroll")                                                 \
            for (int jt = 0; jt < 2; ++jt) {                                  \
                f32x4 acc0 = (f32x4){0.f, 0.f, 0.f, 0.f};                     \
                f32x4 acc1 = (f32x4){0.f, 0.f, 0.f, 0.f};                     \
                __builtin_amdgcn_s_setprio(1);                                \
                _Pragma("unroll")                                             \
                for (int ks = 0; ks < 4; ++ks) {                              \
                    int q = (jt * 16 + l) * 16 + ((ks * 4 + quad) ^ l);       \
                    bf16x8 bfr = *(const bf16x8*)(Bb_ + (size_t)q * 16);      \
                    acc0 = __builtin_amdgcn_mfma_f32_16x16x32_bf16(           \
                        afrag[0][ks], bfr, acc0, 0, 0, 0);                    \
                    acc1 = __builtin_amdgcn_mfma_f32_16x16x32_bf16(           \
                        afrag[1][ks], bfr, acc1, 0, 0, 0);                    \
                }                                                             \
                __builtin_amdgcn_s_setprio(0);                                \
                int jb_ = (h) * 32 + jt * 16;                                 \
                float sjc = sqs[jb_ + l];                                     \
                int   tjc = tgs[jb_ + l];                                     \
                _Pragma("unroll")                                             \
                for (int reg = 0; reg < 4; ++reg) {                           \
                    float t0 = fmaf(-2.0f, acc0[reg], sjc);                   \
                    float t1 = fmaf(-2.0f, acc1[reg], sjc);                   \
                    bool s0 = (li[0][reg] == tjc);                            \
                    bool s1 = (li[1][reg] == tjc);                            \
                    lap[reg]     = fmaxf(lap[reg],     s0 ? t0 : -1e30f);     \
                    lan[reg]     = fminf(lan[reg],     s0 ? 1e30f : t0);      \
                    lap[4 + reg] = fmaxf(lap[4 + reg], s1 ? t1 : -1e30f);     \
                    lan[4 + reg] = fminf(lan[4 + reg], s1 ? 1e30f : t1);      \
                }                                                             \
            }                                                                 \
        } while (0)

    // prologue: 3 half-tiles in flight + metadata staged
    PREF_HALF(0);
    PREF_HALF(1);
    PREF_HALF(2);
    sqs[tid]       = sq[j0 + tid];
    sqs[tid + 256] = sq[j0 + tid + 256];
    tgs[tid]       = tgt[j0 + tid];
    tgs[tid + 256] = tgt[j0 + tid + 256];

    // block phase-stagger: dispatch rounds 0..3 sleep 0/960/1920/2880 cyc
    // (prefetches already in flight, so the sleep is hidden behind them for
    // round 0 and de-convoys rounds 1..3). Perf heuristic only -- no
    // correctness dependence on dispatch order.
    {
        int rnd = ((blockIdx.y * gridDim.x + blockIdx.x) >> 8) & 3;
        #pragma unroll 1
        for (int i = 0; i < rnd; ++i) __builtin_amdgcn_s_sleep(15);
    }
    asm volatile("s_waitcnt lgkmcnt(0)" ::: "memory");

    // steady-state phases: counted vmcnt, one barrier per phase
    for (int h = 0; h < 14; ++h) {
        asm volatile("s_waitcnt vmcnt(4)" ::: "memory");
        __builtin_amdgcn_s_barrier();
        asm volatile("" ::: "memory");       // no load hoisting above barrier
        if (h < 13) PREF_HALF(h + 3);
        COMP_HALF(h);
    }
    // tail phases: drain 2 -> 0
    asm volatile("s_waitcnt vmcnt(2)" ::: "memory");
    __builtin_amdgcn_s_barrier();
    asm volatile("" ::: "memory");
    COMP_HALF(14);
    asm volatile("s_waitcnt vmcnt(0)" ::: "memory");
    __builtin_amdgcn_s_barrier();
    asm volatile("" ::: "memory");
    COMP_HALF(15);

    #undef PREF_HALF
    #undef COMP_HALF

    // reduce across 16 column-lanes (xor<16 stays within quad group),
    // then plain partial store (no atomics)
    #pragma unroll
    for (int mt = 0; mt < 2; ++mt)
        #pragma unroll
        for (int reg = 0; reg < 4; ++reg) {
            float p = lap[mt * 4 + reg], q = lan[mt * 4 + reg];
            #pragma unroll
            for (int o = 1; o < 16; o <<= 1) {
                p = fmaxf(p, __shfl_xor(p, o, 64));
                q = fminf(q, __shfl_xor(q, o, 64));
            }
            if (l == mt * 4 + reg) {   // one writer lane per quad
                int gi = rowbase + mt * 16 + quad * 4 + reg;
                float s = sq[gi];
                pap[(size_t)blockIdx.y * n + gi] = fmaxf(s + p, 0.0f);
                pan[(size_t)blockIdx.y * n + gi] = fmaxf(s + q, 0.0f);
            }
        }
}

// ---------------- final: reduce partials, sum relu(ap - an + margin) -----
__global__ void final_kernel(const float* __restrict__ pap,
                             const float* __restrict__ pan,
                             float* __restrict__ out, int n) {
    int i = blockIdx.x * blockDim.x + threadIdx.x;
    float p = pap[i], q = pan[i];
    #pragma unroll
    for (int s = 1; s < NSPLIT; ++s) {
        p = fmaxf(p, pap[(size_t)s * n + i]);
        q = fminf(q, pan[(size_t)s * n + i]);
    }
    float v = fmaxf(p - q + MARGIN, 0.0f);
    #pragma unroll
    for (int o = 32; o > 0; o >>= 1) v += __shfl_xor(v, o, 64);
    __shared__ float ws[4];
    int lane = threadIdx.x & 63, w = threadIdx.x >> 6;
    if (lane == 0) ws[w] = v;
    __syncthreads();
    if (threadIdx.x == 0) atomicAdd(out, ws[0] + ws[1] + ws[2] + ws[3]);
}

extern "C" void kernel_launch(void* const* d_in, const int* in_sizes, int n_in,
                              void* d_out, int out_size, void* d_ws, size_t ws_size,
                              hipStream_t stream) {
    const float* x   = (const float*)d_in[0];
    const int*   tgt = (const int*)d_in[1];
    float* out = (float*)d_out;
    const int n = in_sizes[1];              // 8192

    // ws layout: sq [n*4] | pap [n*NSPLIT*4] | pan [n*NSPLIT*4] | xb [n*D*2]
    float*          sq  = (float*)d_ws;
    float*          pap = (float*)((char*)d_ws + (size_t)n * 4);
    float*          pan = (float*)((char*)d_ws + (size_t)n * 4 + (size_t)n * NSPLIT * 4);
    __hip_bfloat16* xb  = (__hip_bfloat16*)((char*)d_ws + (size_t)n * 4 + (size_t)n * NSPLIT * 8);

    prep_kernel<<<n / 4, 256, 0, stream>>>(x, sq, xb, out, n);
    dim3 grid(n / 128, NSPLIT);
    gram_kernel<<<grid, 256, 0, stream>>>(xb, sq, tgt, pap, pan, n);
    final_kernel<<<n / 256, 256, 0, stream>>>(pap, pan, out, n);
}